// Round 14
// baseline (333.366 us; speedup 1.0000x reference)
//
#include <hip/hip_runtime.h>
#include <hip/hip_bf16.h>
#include <math.h>

typedef short short8 __attribute__((ext_vector_type(8)));
typedef float f32x16 __attribute__((ext_vector_type(16)));

constexpr int D = 768;    // model dim
constexpr int E = 8;      // experts
constexpr int F = 3072;   // ffn dim
constexpr int T = 8192;   // tokens
constexpr float EPS = 1e-6f;

static __device__ inline unsigned short f2bf(float f) {
    __hip_bfloat16 h = __float2bfloat16(f);
    return *reinterpret_cast<unsigned short*>(&h);
}

static __device__ inline f32x16 mfma_bf16(short8 a, short8 b, f32x16 c) {
    return __builtin_amdgcn_mfma_f32_32x32x16_bf16(a, b, c, 0, 0, 0);
}

// async global->LDS, 16B per lane; LDS dest = wave-uniform base + lane*16
#define GLL16(g, s) __builtin_amdgcn_global_load_lds( \
    (const __attribute__((address_space(1))) unsigned int*)(g), \
    (__attribute__((address_space(3))) unsigned int*)(s), 16, 0, 0)

// ---------------------------------------------------------------------------
// Fused prep: blocks [0, 36864) convert weights (wi'=bf16(wi*ln_w) folded,
// wo'=bf16(wo)); blocks [36864, 38912) run router+RMS-norm.
// ---------------------------------------------------------------------------
__global__ __launch_bounds__(256)
void prep_kernel(const float* __restrict__ wi, const float* __restrict__ wo,
                 const float* __restrict__ lnw,
                 unsigned short* __restrict__ wip, unsigned short* __restrict__ wop,
                 const float* __restrict__ x, const float* __restrict__ rw,
                 float* __restrict__ logits, unsigned short* __restrict__ xn,
                 float* __restrict__ out, int* __restrict__ sel,
                 float2* __restrict__ w01)
{
    if (blockIdx.x < 36864) {
        // ---- weight conversion ----
        const unsigned NWI = (unsigned)E * F * D;
        unsigned i4 = (blockIdx.x * 256u + threadIdx.x) * 4u;
        if (i4 < NWI) {
            float4 v = *(const float4*)(wi + i4);
            unsigned e = i4 / (unsigned)(F * D);
            unsigned d = i4 % (unsigned)D;
            float4 l = *(const float4*)(lnw + e * D + d);
            ushort4 o = { f2bf(v.x * l.x), f2bf(v.y * l.y), f2bf(v.z * l.z), f2bf(v.w * l.w) };
            *(ushort4*)(wip + i4) = o;
        } else {
            unsigned j = i4 - NWI;
            float4 v = *(const float4*)(wo + j);
            ushort4 o = { f2bf(v.x), f2bf(v.y), f2bf(v.z), f2bf(v.w) };
            *(ushort4*)(wop + j) = o;
        }
        return;
    }

    // ---- router + RMS-norm (one 64-lane wave per token) ----
    const int lane = threadIdx.x & 63;
    const int wid  = threadIdx.x >> 6;
    const int t = (blockIdx.x - 36864) * 4 + wid;
    if (t >= T) return;

    const float* xr = x + (size_t)t * D;
    float xv[12];
    float acc[8];
#pragma unroll
    for (int e = 0; e < 8; ++e) acc[e] = 0.f;
    float ssq = 0.f;
#pragma unroll
    for (int i = 0; i < 12; ++i) {
        const int k = lane + 64 * i;
        const float v = xr[k];
        xv[i] = v;
        ssq += v * v;
#pragma unroll
        for (int e = 0; e < 8; ++e) acc[e] += v * rw[e * D + k];
    }
#pragma unroll
    for (int off = 32; off; off >>= 1) {
        ssq += __shfl_xor(ssq, off);
#pragma unroll
        for (int e = 0; e < 8; ++e) acc[e] += __shfl_xor(acc[e], off);
    }

    int e0 = 0; float m0 = acc[0];
#pragma unroll
    for (int e = 1; e < 8; ++e) if (acc[e] > m0) { m0 = acc[e]; e0 = e; }
    int e1 = -1; float m1 = -3.4e38f;
#pragma unroll
    for (int e = 0; e < 8; ++e) if (e != e0 && acc[e] > m1) { m1 = acc[e]; e1 = e; }

    const float r  = expf(m1 - m0);
    const float w0 = 1.f / (1.f + r);
    const float w1 = r * w0;
    const float wsum = w0 + w1;
    const float rs = rsqrtf(ssq * (1.f / (float)D) + EPS);

    if (lane == 0) {
#pragma unroll
        for (int e = 0; e < 8; ++e) logits[t * 8 + e] = acc[e];
        sel[t] = e0 | (e1 << 4);
        w01[t] = make_float2(w0, w1);
    }

#pragma unroll
    for (int i = 0; i < 12; ++i) {
        const int k = lane + 64 * i;
        xn[(size_t)t * D + k] = f2bf(xv[i] * rs);
        out[(size_t)t * D + k] = wsum * xv[i];
    }
}

// ---------------------------------------------------------------------------
// List build, ONE kernel, 8 blocks (one per expert). Zero atomics.
// ---------------------------------------------------------------------------
__global__ __launch_bounds__(256)
void lists_kernel(const int* __restrict__ sel, const float2* __restrict__ w01,
                  int* __restrict__ offs,
                  int* __restrict__ lists, float* __restrict__ wlist)
{
    const int e = blockIdx.x;
    const int tid = threadIdx.x;
    const int lane = tid & 63;
    const int wv = tid >> 6;

    __shared__ int sc[4][8];
    __shared__ int wtot[4];

    int c[8];
#pragma unroll
    for (int i = 0; i < 8; ++i) c[i] = 0;
    for (int t = tid; t < T; t += 256) {
        const int s = sel[t];
        const int a = s & 15, b = (s >> 4) & 15;
#pragma unroll
        for (int i = 0; i < 8; ++i) c[i] += (a == i) + (b == i);
    }
#pragma unroll
    for (int off = 32; off; off >>= 1)
#pragma unroll
        for (int i = 0; i < 8; ++i) c[i] += __shfl_xor(c[i], off);
    if (lane == 0)
#pragma unroll
        for (int i = 0; i < 8; ++i) sc[wv][i] = c[i];
    __syncthreads();

    int cnt8[8];
#pragma unroll
    for (int i = 0; i < 8; ++i) cnt8[i] = sc[0][i] + sc[1][i] + sc[2][i] + sc[3][i];
    int base = 0;
#pragma unroll
    for (int i = 0; i < 8; ++i) if (i < e) base += cnt8[i];

    if (e == 0 && tid == 0) {
        int a = 0;
#pragma unroll
        for (int i = 0; i < 8; ++i) { offs[i] = a; a += cnt8[i]; }
        offs[8] = a;
    }

    int cnt = 0;
    for (int c0 = 0; c0 < T; c0 += 256) {
        const int t = c0 + tid;
        const int s = sel[t];
        const bool m1 = ((s >> 4) & 15) == e;
        const bool m = ((s & 15) == e) || m1;
        const unsigned long long b = __ballot(m);
        const int pre = __popcll(b & ((1ULL << lane) - 1ULL));
        if (lane == 0) wtot[wv] = __popcll(b);
        __syncthreads();
        int wbase = 0;
#pragma unroll
        for (int i = 0; i < 4; ++i) if (i < wv) wbase += wtot[i];
        if (m) {
            const int pos = base + cnt + wbase + pre;
            lists[pos] = (t << 1) | (m1 ? 1 : 0);
            const float2 w = w01[t];
            wlist[pos] = m1 ? w.y : w.x;
        }
        cnt += wtot[0] + wtot[1] + wtot[2] + wtot[3];
        __syncthreads();
    }
}

// ===========================================================================
// Single-buffer 128x128 GEMM core (r6/r10-proven): BK=64, 4 waves, 33 KB LDS
// -> 4 blocks/CU resident; cross-block TLP hides the stage drain (m114).
// Rule-21 swizzle: linear LDS dest + inverse-swizzled global src + swz read.
// ===========================================================================

// ---------------------------------------------------------------------------
// GEMM1: H[offs[e]+row][f] = relu( xn[tok(row)] . wip[e][f] ), full F.
// grid: ((mt*24 + nt) << 3) | e, mt < 64 (worst-case imbalance safe).
// ---------------------------------------------------------------------------
__global__ __launch_bounds__(256)
void gemm1_kernel(const unsigned short* __restrict__ xn,
                  const unsigned short* __restrict__ wip,
                  const int* __restrict__ offs,
                  const int* __restrict__ lists,
                  unsigned short* __restrict__ H)
{
    __shared__ unsigned short sA[128 * 64];
    __shared__ unsigned short sB[128 * 64];
    __shared__ int s_tok[128];

    const int bid = blockIdx.x;
    const int e  = bid & 7;
    const int q  = bid >> 3;
    const int mt = q / 24;
    const int nt = q % 24;
    const int offe = offs[e];
    const int cnt = offs[e + 1] - offe;
    const int base = mt * 128;
    if (base >= cnt) return;

    const int tid = threadIdx.x;
    const int w = tid >> 6, l = tid & 63;
    const int lo = l & 31, hi = l >> 5;
    const int wr = w >> 1, wc = w & 1;

    if (tid < 128) {
        const int idx = base + tid;
        s_tok[tid] = (idx < cnt) ? (lists[offe + idx] >> 1) : 0;
    }
    __syncthreads();

    const int r = (w * 4 + 0) * 8 + (l >> 3);
    const int chS = ((l & 7) ^ ((l >> 3) & 7)) * 8;
    const unsigned short* aSrc[4];
    const unsigned short* bSrc[4];
#pragma unroll
    for (int j = 0; j < 4; ++j) {
        const int rj = r + j * 8;
        aSrc[j] = xn + (size_t)s_tok[rj] * D + chS;
        bSrc[j] = wip + ((size_t)e * F + nt * 128 + rj) * D + chS;
    }
    char* sAc = (char*)sA;
    char* sBc = (char*)sB;

    f32x16 acc00, acc01, acc10, acc11;
#pragma unroll
    for (int qq = 0; qq < 16; ++qq) { acc00[qq] = 0.f; acc01[qq] = 0.f; acc10[qq] = 0.f; acc11[qq] = 0.f; }

    const int rx = (lo & 7) << 4;
    const int arow0 = (wr * 64 + lo) * 128;
    const int arow1 = arow0 + 32 * 128;
    const int brow0 = (wc * 64 + lo) * 128;
    const int brow1 = brow0 + 32 * 128;

    for (int kt = 0; kt < 12; ++kt) {               // K = 768
        const int k0 = kt * 64;
#pragma unroll
        for (int j = 0; j < 4; ++j) {
            GLL16(aSrc[j] + k0, sAc + (w * 4 + j) * 1024);
            GLL16(bSrc[j] + k0, sBc + (w * 4 + j) * 1024);
        }
        __syncthreads();
#pragma unroll
        for (int ks = 0; ks < 4; ++ks) {
            const int coff = (hi * 16 + ks * 32) ^ rx;
            short8 a0 = *(const short8*)(sAc + arow0 + coff);
            short8 a1 = *(const short8*)(sAc + arow1 + coff);
            short8 b0 = *(const short8*)(sBc + brow0 + coff);
            short8 b1 = *(const short8*)(sBc + brow1 + coff);
            acc00 = mfma_bf16(a0, b0, acc00);
            acc01 = mfma_bf16(a0, b1, acc01);
            acc10 = mfma_bf16(a1, b0, acc10);
            acc11 = mfma_bf16(a1, b1, acc11);
        }
        __syncthreads();
    }

    // epilogue: relu -> bf16 -> H (rows >= cnt clamped; packed full-F layout)
    const int cbase = nt * 128 + wc * 64 + lo;
#pragma unroll
    for (int rr = 0; rr < 16; ++rr) {
        const int crow = (rr & 3) + 8 * (rr >> 2) + 4 * hi;
        int lrow = wr * 64 + crow;
        if (base + lrow < cnt) {
            unsigned short* hp = H + (size_t)(offe + base + lrow) * F + cbase;
            hp[0]  = f2bf(fmaxf(acc00[rr], 0.f));
            hp[32] = f2bf(fmaxf(acc01[rr], 0.f));
        }
        lrow += 32;
        if (base + lrow < cnt) {
            unsigned short* hp = H + (size_t)(offe + base + lrow) * F + cbase;
            hp[0]  = f2bf(fmaxf(acc10[rr], 0.f));
            hp[32] = f2bf(fmaxf(acc11[rr], 0.f));
        }
    }
}

// ---------------------------------------------------------------------------
// GEMM2: ffout[kh][slot][tok][d] = w_tok * ( H[row][kh-range] . wop[e][d][kh] )
// kts = 48/nkh K-steps per block. Each (kh,slot,tok,d) has exactly ONE
// writer -> plain f32 stores, ZERO atomics.
// nkh=1: r13-proven config (768 active blocks). nkh=2: 1536 active blocks
// (gemm1's queue depth) with the second buffer past the ws watermark.
// grid: ((kh*384 + mt*6 + nt) << 3) | e, mt < 64.
// ---------------------------------------------------------------------------
__global__ __launch_bounds__(256)
void gemm2_kernel(const unsigned short* __restrict__ H,
                  const unsigned short* __restrict__ wop,
                  const int* __restrict__ offs,
                  const int* __restrict__ lists, const float* __restrict__ wlist,
                  float* __restrict__ ffout0, float* __restrict__ ffout1,
                  int kts)
{
    __shared__ unsigned short sA[128 * 64];
    __shared__ unsigned short sB[128 * 64];
    __shared__ int   s_tok[128];
    __shared__ float s_wgt[128];

    const int bid = blockIdx.x;
    const int e  = bid & 7;
    const int q  = bid >> 3;
    const int kh = q / 384;
    const int rm = q % 384;
    const int mt = rm / 6;
    const int nt = rm % 6;
    const int offe = offs[e];
    const int cnt = offs[e + 1] - offe;
    const int base = mt * 128;
    if (base >= cnt) return;

    const int tid = threadIdx.x;
    const int w = tid >> 6, l = tid & 63;
    const int lo = l & 31, hi = l >> 5;
    const int wr = w >> 1, wc = w & 1;

    if (tid < 128) {
        const int idx = base + tid;
        const bool v = idx < cnt;
        s_tok[tid] = v ? lists[offe + idx] : 0;
        s_wgt[tid] = v ? wlist[offe + idx] : 0.f;
    }
    __syncthreads();

    const int kof = kh * kts * 64;                  // K-range start
    const int r = (w * 4 + 0) * 8 + (l >> 3);
    const int chS = ((l & 7) ^ ((l >> 3) & 7)) * 8;
    const unsigned short* aSrc[4];
    const unsigned short* bSrc[4];
#pragma unroll
    for (int j = 0; j < 4; ++j) {
        const int rj = r + j * 8;
        aSrc[j] = H + (size_t)(offe + base + rj) * F + kof + chS;
        bSrc[j] = wop + ((size_t)e * D + nt * 128 + rj) * F + kof + chS;
    }
    char* sAc = (char*)sA;
    char* sBc = (char*)sB;

    f32x16 acc00, acc01, acc10, acc11;
#pragma unroll
    for (int qq = 0; qq < 16; ++qq) { acc00[qq] = 0.f; acc01[qq] = 0.f; acc10[qq] = 0.f; acc11[qq] = 0.f; }

    const int rx = (lo & 7) << 4;
    const int arow0 = (wr * 64 + lo) * 128;
    const int arow1 = arow0 + 32 * 128;
    const int brow0 = (wc * 64 + lo) * 128;
    const int brow1 = brow0 + 32 * 128;

    for (int kt = 0; kt < kts; ++kt) {
        const int k0 = kt * 64;
#pragma unroll
        for (int j = 0; j < 4; ++j) {
            GLL16(aSrc[j] + k0, sAc + (w * 4 + j) * 1024);
            GLL16(bSrc[j] + k0, sBc + (w * 4 + j) * 1024);
        }
        __syncthreads();
#pragma unroll
        for (int ks = 0; ks < 4; ++ks) {
            const int coff = (hi * 16 + ks * 32) ^ rx;
            short8 a0 = *(const short8*)(sAc + arow0 + coff);
            short8 a1 = *(const short8*)(sAc + arow1 + coff);
            short8 b0 = *(const short8*)(sBc + brow0 + coff);
            short8 b1 = *(const short8*)(sBc + brow1 + coff);
            acc00 = mfma_bf16(a0, b0, acc00);
            acc01 = mfma_bf16(a0, b1, acc01);
            acc10 = mfma_bf16(a1, b0, acc10);
            acc11 = mfma_bf16(a1, b1, acc11);
        }
        __syncthreads();
    }

    float* fbase = kh ? ffout1 : ffout0;
    const int cbase = nt * 128 + wc * 64 + lo;
#pragma unroll
    for (int rr = 0; rr < 16; ++rr) {
        const int crow = (rr & 3) + 8 * (rr >> 2) + 4 * hi;
#pragma unroll
        for (int mh = 0; mh < 2; ++mh) {
            const int lrow = wr * 64 + crow + mh * 32;
            if (base + lrow < cnt) {
                const int pk = s_tok[lrow];
                const float wgt = s_wgt[lrow];
                float* dst = fbase + ((size_t)(pk & 1) * T + (pk >> 1)) * D + cbase;
                dst[0]  = wgt * (mh ? acc10[rr] : acc00[rr]);
                dst[32] = wgt * (mh ? acc11[rr] : acc01[rr]);
            }
        }
    }
}

// ---------------------------------------------------------------------------
// Combine: out (= wsum*x from prep) += sum of ffout partials.
// nkh==1: 2 buffers (ffout0 slots); nkh==2: 4 buffers (+ffout1 slots).
// ---------------------------------------------------------------------------
__global__ __launch_bounds__(256)
void combine_kernel(const float* __restrict__ f0, const float* __restrict__ f1,
                    int nkh, float* __restrict__ out)
{
    const long long i4 = ((long long)blockIdx.x * 256 + threadIdx.x) * 4;
    float4 o  = *(const float4*)(out + i4);
    float4 a0 = *(const float4*)(f0 + i4);
    float4 a1 = *(const float4*)(f0 + (long long)T * D + i4);
    o.x += a0.x + a1.x; o.y += a0.y + a1.y;
    o.z += a0.z + a1.z; o.w += a0.w + a1.w;
    if (nkh == 2) {
        float4 b0 = *(const float4*)(f1 + i4);
        float4 b1 = *(const float4*)(f1 + (long long)T * D + i4);
        o.x += b0.x + b1.x; o.y += b0.y + b1.y;
        o.z += b0.z + b1.z; o.w += b0.w + b1.w;
    }
    *(float4*)(out + i4) = o;
}

// ---------------------------------------------------------------------------
extern "C" void kernel_launch(void* const* d_in, const int* in_sizes, int n_in,
                              void* d_out, int out_size, void* d_ws, size_t ws_size,
                              hipStream_t stream) {
    const float* x   = (const float*)d_in[0];   // [T, D]
    const float* rw  = (const float*)d_in[1];   // [E, D]
    const float* lnw = (const float*)d_in[2];   // [E, D]
    const float* wi  = (const float*)d_in[3];   // [E, F, D]
    const float* wo  = (const float*)d_in[4];   // [E, D, F]

    float* out    = (float*)d_out;                    // [T, D]
    float* logits = (float*)d_out + (size_t)T * D;    // [T, E]

    // Proven base layout (watermark 190,578,688 B). ffout0 OVERLAYS xn+wip
    // (dead after gemm1; region [0, 50331648) == [2][T][D] f32 exactly).
    // ffout1 (nkh=2 only) appended past the watermark: +50,331,648 B.
    char* ws = (char*)d_ws;
    unsigned short* xn     = (unsigned short*)(ws);               // 12.58 MB
    unsigned short* wip    = (unsigned short*)(ws + 12582912);    // 37.75 MB
    float*          ffout0 = (float*)(ws);                        // 50.33 MB overlay
    unsigned short* wop    = (unsigned short*)(ws + 50331648);    // 37.75 MB
    unsigned short* H      = (unsigned short*)(ws + 88080384);    // 16640 x 3072 bf16
    int*            offs   = (int*)(ws + 190316544);              // 64 B (9 ints)
    int*            sel    = (int*)(ws + 190316672);              // 32 KB
    float2*         w01    = (float2*)(ws + 190349440);           // 64 KB
    int*            lists  = (int*)(ws + 190414976);              // 64 KB
    float*          wlist  = (float*)(ws + 190480512);            // 64 KB
    float*          ffout1 = (float*)(ws + 190578688);            // 50.33 MB (optional)

    // Deterministic per deployment: ws_size is fixed.
    const bool big2 = ws_size >= 240910336ULL;
    const int nkh = big2 ? 2 : 1;
    const int kts = 48 / nkh;

    // fused convert + router
    prep_kernel<<<36864 + T / 4, 256, 0, stream>>>(wi, wo, lnw, wip, wop,
                                                   x, rw, logits, xn, out,
                                                   sel, w01);

    lists_kernel<<<E, 256, 0, stream>>>(sel, w01, offs, lists, wlist);

    // worst-case grids (mt < 64 covers any expert imbalance); dead blocks exit
    gemm1_kernel<<<64 * 24 * 8, 256, 0, stream>>>(xn, wip, offs, lists, H);
    gemm2_kernel<<<nkh * 64 * 6 * 8, 256, 0, stream>>>(H, wop, offs, lists,
                                                       wlist, ffout0,
                                                       big2 ? ffout1 : ffout0,
                                                       kts);
    combine_kernel<<<T * D / 4 / 256, 256, 0, stream>>>(ffout0,
                                                        big2 ? ffout1 : ffout0,
                                                        nkh, out);
}

// Round 15
// 316.226 us; speedup vs baseline: 1.0542x; 1.0542x over previous
//
#include <hip/hip_runtime.h>
#include <hip/hip_bf16.h>
#include <math.h>

typedef short short8 __attribute__((ext_vector_type(8)));
typedef float f32x16 __attribute__((ext_vector_type(16)));

constexpr int D = 768;    // model dim
constexpr int E = 8;      // experts
constexpr int F = 3072;   // ffn dim
constexpr int T = 8192;   // tokens
constexpr float EPS = 1e-6f;

static __device__ inline unsigned short f2bf(float f) {
    __hip_bfloat16 h = __float2bfloat16(f);
    return *reinterpret_cast<unsigned short*>(&h);
}

static __device__ inline f32x16 mfma_bf16(short8 a, short8 b, f32x16 c) {
    return __builtin_amdgcn_mfma_f32_32x32x16_bf16(a, b, c, 0, 0, 0);
}

// async global->LDS, 16B per lane; LDS dest = wave-uniform base + lane*16
#define GLL16(g, s) __builtin_amdgcn_global_load_lds( \
    (const __attribute__((address_space(1))) unsigned int*)(g), \
    (__attribute__((address_space(3))) unsigned int*)(s), 16, 0, 0)

// ---------------------------------------------------------------------------
// Fused prep: blocks [0, 36864) convert weights (wi'=bf16(wi*ln_w) folded,
// wo'=bf16(wo)); blocks [36864, 38912) run router+RMS-norm.
// (No out-prefill: combine reconstructs wsum*x from x and w01.)
// ---------------------------------------------------------------------------
__global__ __launch_bounds__(256)
void prep_kernel(const float* __restrict__ wi, const float* __restrict__ wo,
                 const float* __restrict__ lnw,
                 unsigned short* __restrict__ wip, unsigned short* __restrict__ wop,
                 const float* __restrict__ x, const float* __restrict__ rw,
                 float* __restrict__ logits, unsigned short* __restrict__ xn,
                 int* __restrict__ sel, float2* __restrict__ w01)
{
    if (blockIdx.x < 36864) {
        const unsigned NWI = (unsigned)E * F * D;
        unsigned i4 = (blockIdx.x * 256u + threadIdx.x) * 4u;
        if (i4 < NWI) {
            float4 v = *(const float4*)(wi + i4);
            unsigned e = i4 / (unsigned)(F * D);
            unsigned d = i4 % (unsigned)D;
            float4 l = *(const float4*)(lnw + e * D + d);
            ushort4 o = { f2bf(v.x * l.x), f2bf(v.y * l.y), f2bf(v.z * l.z), f2bf(v.w * l.w) };
            *(ushort4*)(wip + i4) = o;
        } else {
            unsigned j = i4 - NWI;
            float4 v = *(const float4*)(wo + j);
            ushort4 o = { f2bf(v.x), f2bf(v.y), f2bf(v.z), f2bf(v.w) };
            *(ushort4*)(wop + j) = o;
        }
        return;
    }

    // ---- router + RMS-norm (one 64-lane wave per token) ----
    const int lane = threadIdx.x & 63;
    const int wid  = threadIdx.x >> 6;
    const int t = (blockIdx.x - 36864) * 4 + wid;
    if (t >= T) return;

    const float* xr = x + (size_t)t * D;
    float xv[12];
    float acc[8];
#pragma unroll
    for (int e = 0; e < 8; ++e) acc[e] = 0.f;
    float ssq = 0.f;
#pragma unroll
    for (int i = 0; i < 12; ++i) {
        const int k = lane + 64 * i;
        const float v = xr[k];
        xv[i] = v;
        ssq += v * v;
#pragma unroll
        for (int e = 0; e < 8; ++e) acc[e] += v * rw[e * D + k];
    }
#pragma unroll
    for (int off = 32; off; off >>= 1) {
        ssq += __shfl_xor(ssq, off);
#pragma unroll
        for (int e = 0; e < 8; ++e) acc[e] += __shfl_xor(acc[e], off);
    }

    int e0 = 0; float m0 = acc[0];
#pragma unroll
    for (int e = 1; e < 8; ++e) if (acc[e] > m0) { m0 = acc[e]; e0 = e; }
    int e1 = -1; float m1 = -3.4e38f;
#pragma unroll
    for (int e = 0; e < 8; ++e) if (e != e0 && acc[e] > m1) { m1 = acc[e]; e1 = e; }

    const float r  = expf(m1 - m0);
    const float w0 = 1.f / (1.f + r);
    const float w1 = r * w0;
    const float rs = rsqrtf(ssq * (1.f / (float)D) + EPS);

    if (lane == 0) {
#pragma unroll
        for (int e = 0; e < 8; ++e) logits[t * 8 + e] = acc[e];
        sel[t] = e0 | (e1 << 4);
        w01[t] = make_float2(w0, w1);
    }

#pragma unroll
    for (int i = 0; i < 12; ++i) {
        const int k = lane + 64 * i;
        xn[(size_t)t * D + k] = f2bf(xv[i] * rs);
    }
}

// ---------------------------------------------------------------------------
// List build, ONE kernel, 8 blocks (one per expert). Zero atomics.
// ---------------------------------------------------------------------------
__global__ __launch_bounds__(256)
void lists_kernel(const int* __restrict__ sel, const float2* __restrict__ w01,
                  int* __restrict__ offs,
                  int* __restrict__ lists, float* __restrict__ wlist)
{
    const int e = blockIdx.x;
    const int tid = threadIdx.x;
    const int lane = tid & 63;
    const int wv = tid >> 6;

    __shared__ int sc[4][8];
    __shared__ int wtot[4];

    int c[8];
#pragma unroll
    for (int i = 0; i < 8; ++i) c[i] = 0;
    for (int t = tid; t < T; t += 256) {
        const int s = sel[t];
        const int a = s & 15, b = (s >> 4) & 15;
#pragma unroll
        for (int i = 0; i < 8; ++i) c[i] += (a == i) + (b == i);
    }
#pragma unroll
    for (int off = 32; off; off >>= 1)
#pragma unroll
        for (int i = 0; i < 8; ++i) c[i] += __shfl_xor(c[i], off);
    if (lane == 0)
#pragma unroll
        for (int i = 0; i < 8; ++i) sc[wv][i] = c[i];
    __syncthreads();

    int cnt8[8];
#pragma unroll
    for (int i = 0; i < 8; ++i) cnt8[i] = sc[0][i] + sc[1][i] + sc[2][i] + sc[3][i];
    int base = 0;
#pragma unroll
    for (int i = 0; i < 8; ++i) if (i < e) base += cnt8[i];

    if (e == 0 && tid == 0) {
        int a = 0;
#pragma unroll
        for (int i = 0; i < 8; ++i) { offs[i] = a; a += cnt8[i]; }
        offs[8] = a;
    }

    int cnt = 0;
    for (int c0 = 0; c0 < T; c0 += 256) {
        const int t = c0 + tid;
        const int s = sel[t];
        const bool m1 = ((s >> 4) & 15) == e;
        const bool m = ((s & 15) == e) || m1;
        const unsigned long long b = __ballot(m);
        const int pre = __popcll(b & ((1ULL << lane) - 1ULL));
        if (lane == 0) wtot[wv] = __popcll(b);
        __syncthreads();
        int wbase = 0;
#pragma unroll
        for (int i = 0; i < 4; ++i) if (i < wv) wbase += wtot[i];
        if (m) {
            const int pos = base + cnt + wbase + pre;
            lists[pos] = (t << 1) | (m1 ? 1 : 0);
            const float2 w = w01[t];
            wlist[pos] = m1 ? w.y : w.x;
        }
        cnt += wtot[0] + wtot[1] + wtot[2] + wtot[3];
        __syncthreads();
    }
}

// ---------------------------------------------------------------------------
// GEMM1 (r6/r10-proven, unchanged): H[offs[e]+row][f] = relu(xn . wip),
// 128x128 tile, 4 waves, single-buffer, rule-21 swizzle.
// grid: ((mt*24 + nt) << 3) | e, mt < 64.
// ---------------------------------------------------------------------------
__global__ __launch_bounds__(256)
void gemm1_kernel(const unsigned short* __restrict__ xn,
                  const unsigned short* __restrict__ wip,
                  const int* __restrict__ offs,
                  const int* __restrict__ lists,
                  unsigned short* __restrict__ H)
{
    __shared__ unsigned short sA[128 * 64];
    __shared__ unsigned short sB[128 * 64];
    __shared__ int s_tok[128];

    const int bid = blockIdx.x;
    const int e  = bid & 7;
    const int q  = bid >> 3;
    const int mt = q / 24;
    const int nt = q % 24;
    const int offe = offs[e];
    const int cnt = offs[e + 1] - offe;
    const int base = mt * 128;
    if (base >= cnt) return;

    const int tid = threadIdx.x;
    const int w = tid >> 6, l = tid & 63;
    const int lo = l & 31, hi = l >> 5;
    const int wr = w >> 1, wc = w & 1;

    if (tid < 128) {
        const int idx = base + tid;
        s_tok[tid] = (idx < cnt) ? (lists[offe + idx] >> 1) : 0;
    }
    __syncthreads();

    const int r = (w * 4 + 0) * 8 + (l >> 3);
    const int chS = ((l & 7) ^ ((l >> 3) & 7)) * 8;
    const unsigned short* aSrc[4];
    const unsigned short* bSrc[4];
#pragma unroll
    for (int j = 0; j < 4; ++j) {
        const int rj = r + j * 8;
        aSrc[j] = xn + (size_t)s_tok[rj] * D + chS;
        bSrc[j] = wip + ((size_t)e * F + nt * 128 + rj) * D + chS;
    }
    char* sAc = (char*)sA;
    char* sBc = (char*)sB;

    f32x16 acc00, acc01, acc10, acc11;
#pragma unroll
    for (int qq = 0; qq < 16; ++qq) { acc00[qq] = 0.f; acc01[qq] = 0.f; acc10[qq] = 0.f; acc11[qq] = 0.f; }

    const int rx = (lo & 7) << 4;
    const int arow0 = (wr * 64 + lo) * 128;
    const int arow1 = arow0 + 32 * 128;
    const int brow0 = (wc * 64 + lo) * 128;
    const int brow1 = brow0 + 32 * 128;

    for (int kt = 0; kt < 12; ++kt) {               // K = 768
        const int k0 = kt * 64;
#pragma unroll
        for (int j = 0; j < 4; ++j) {
            GLL16(aSrc[j] + k0, sAc + (w * 4 + j) * 1024);
            GLL16(bSrc[j] + k0, sBc + (w * 4 + j) * 1024);
        }
        __syncthreads();
#pragma unroll
        for (int ks = 0; ks < 4; ++ks) {
            const int coff = (hi * 16 + ks * 32) ^ rx;
            short8 a0 = *(const short8*)(sAc + arow0 + coff);
            short8 a1 = *(const short8*)(sAc + arow1 + coff);
            short8 b0 = *(const short8*)(sBc + brow0 + coff);
            short8 b1 = *(const short8*)(sBc + brow1 + coff);
            acc00 = mfma_bf16(a0, b0, acc00);
            acc01 = mfma_bf16(a0, b1, acc01);
            acc10 = mfma_bf16(a1, b0, acc10);
            acc11 = mfma_bf16(a1, b1, acc11);
        }
        __syncthreads();
    }

    const int cbase = nt * 128 + wc * 64 + lo;
#pragma unroll
    for (int rr = 0; rr < 16; ++rr) {
        const int crow = (rr & 3) + 8 * (rr >> 2) + 4 * hi;
        int lrow = wr * 64 + crow;
        if (base + lrow < cnt) {
            unsigned short* hp = H + (size_t)(offe + base + lrow) * F + cbase;
            hp[0]  = f2bf(fmaxf(acc00[rr], 0.f));
            hp[32] = f2bf(fmaxf(acc01[rr], 0.f));
        }
        lrow += 32;
        if (base + lrow < cnt) {
            unsigned short* hp = H + (size_t)(offe + base + lrow) * F + cbase;
            hp[0]  = f2bf(fmaxf(acc10[rr], 0.f));
            hp[32] = f2bf(fmaxf(acc11[rr], 0.f));
        }
    }
}

// ---------------------------------------------------------------------------
// GEMM2: 128-token x 256-d tile, 8 waves (512 thr), wave-tile 64x64 (the
// byte-proven 2x2-frag inner loop). A(H, rows 0-127) + B(wop, rows 128-383)
// in ONE contiguous 48 KB LDS array; 6 GLL16/wave/K-step. H re-read 3x
// (vs 6x at 128-wide d-tiles). kts = 48/nkh. Plain f32 stores, no atomics.
// grid: ((kh*192 + mt*3 + nt) << 3) | e, mt < 64.
// ---------------------------------------------------------------------------
__global__ __launch_bounds__(512)
void gemm2_kernel(const unsigned short* __restrict__ H,
                  const unsigned short* __restrict__ wop,
                  const int* __restrict__ offs,
                  const int* __restrict__ lists, const float* __restrict__ wlist,
                  float* __restrict__ ffout0, float* __restrict__ ffout1,
                  int kts)
{
    __shared__ unsigned short sT[384 * 64];   // rows 0-127 A(H), 128-383 B(wop)
    __shared__ int   s_tok[128];
    __shared__ float s_wgt[128];

    const int bid = blockIdx.x;
    const int e  = bid & 7;
    const int q  = bid >> 3;
    const int kh = q / 192;
    const int rm = q % 192;
    const int mt = rm / 3;
    const int nt = rm % 3;
    const int offe = offs[e];
    const int cnt = offs[e + 1] - offe;
    const int base = mt * 128;
    if (base >= cnt) return;

    const int tid = threadIdx.x;
    const int w = tid >> 6, l = tid & 63;
    const int lo = l & 31, hi = l >> 5;
    const int wr = w >> 2;        // token-half 0/1
    const int wcn = w & 3;        // d-quarter 0..3

    if (tid < 128) {
        const int idx = base + tid;
        const bool v = idx < cnt;
        s_tok[tid] = v ? lists[offe + idx] : 0;
        s_wgt[tid] = v ? wlist[offe + idx] : 0.f;
    }
    __syncthreads();

    const int kof = kh * kts * 64;                  // K-range start
    const int srow = tid >> 3;                       // 0..63
    const int chS = ((tid & 7) ^ (srow & 7)) * 8;    // inverse-swizzled chunk
    const unsigned short* src6[6];
#pragma unroll
    for (int c = 0; c < 6; ++c) {
        const int rrow = srow + c * 64;              // 0..383
        if (rrow < 128) {
            src6[c] = H + (size_t)(offe + base + rrow) * F + kof + chS;
        } else {
            src6[c] = wop + ((size_t)e * D + nt * 256 + (rrow - 128)) * F + kof + chS;
        }
    }
    char* sTc = (char*)sT;
    const int dOff = srow * 128 + (tid & 7) * 16;    // linear LDS dest (row 0 base)

    f32x16 acc00, acc01, acc10, acc11;
#pragma unroll
    for (int qq = 0; qq < 16; ++qq) { acc00[qq] = 0.f; acc01[qq] = 0.f; acc10[qq] = 0.f; acc11[qq] = 0.f; }

    const int rx = (lo & 7) << 4;
    const int arow0 = (wr * 64 + lo) * 128;
    const int arow1 = arow0 + 32 * 128;
    const int brow0 = (128 + wcn * 64 + lo) * 128;
    const int brow1 = brow0 + 32 * 128;

    for (int kt = 0; kt < kts; ++kt) {
        const int k0 = kt * 64;
#pragma unroll
        for (int c = 0; c < 6; ++c)
            GLL16(src6[c] + k0, sTc + c * 8192 + dOff);
        __syncthreads();
#pragma unroll
        for (int ks = 0; ks < 4; ++ks) {
            const int coff = (hi * 16 + ks * 32) ^ rx;
            short8 a0 = *(const short8*)(sTc + arow0 + coff);
            short8 a1 = *(const short8*)(sTc + arow1 + coff);
            short8 b0 = *(const short8*)(sTc + brow0 + coff);
            short8 b1 = *(const short8*)(sTc + brow1 + coff);
            acc00 = mfma_bf16(a0, b0, acc00);
            acc01 = mfma_bf16(a0, b1, acc01);
            acc10 = mfma_bf16(a1, b0, acc10);
            acc11 = mfma_bf16(a1, b1, acc11);
        }
        __syncthreads();
    }

    float* fbase = kh ? ffout1 : ffout0;
    const int cbase = nt * 256 + wcn * 64 + lo;
#pragma unroll
    for (int rr = 0; rr < 16; ++rr) {
        const int crow = (rr & 3) + 8 * (rr >> 2) + 4 * hi;
#pragma unroll
        for (int mh = 0; mh < 2; ++mh) {
            const int lrow = wr * 64 + crow + mh * 32;
            if (base + lrow < cnt) {
                const int pk = s_tok[lrow];
                const float wgt = s_wgt[lrow];
                float* dst = fbase + ((size_t)(pk & 1) * T + (pk >> 1)) * D + cbase;
                dst[0]  = wgt * (mh ? acc10[rr] : acc00[rr]);
                dst[32] = wgt * (mh ? acc11[rr] : acc01[rr]);
            }
        }
    }
}

// ---------------------------------------------------------------------------
// Combine: out = wsum*x + sum of ffout partials (wsum from w01).
// ---------------------------------------------------------------------------
__global__ __launch_bounds__(256)
void combine_kernel(const float* __restrict__ x, const float2* __restrict__ w01,
                    const float* __restrict__ f0, const float* __restrict__ f1,
                    int nkh, float* __restrict__ out)
{
    const long long i4 = ((long long)blockIdx.x * 256 + threadIdx.x) * 4;
    const int t = (int)(i4 / D);
    const float2 wp = w01[t];
    const float ws = wp.x + wp.y;
    float4 xv = *(const float4*)(x + i4);
    float4 a0 = *(const float4*)(f0 + i4);
    float4 a1 = *(const float4*)(f0 + (long long)T * D + i4);
    float4 o = { ws * xv.x + a0.x + a1.x, ws * xv.y + a0.y + a1.y,
                 ws * xv.z + a0.z + a1.z, ws * xv.w + a0.w + a1.w };
    if (nkh == 2) {
        float4 b0 = *(const float4*)(f1 + i4);
        float4 b1 = *(const float4*)(f1 + (long long)T * D + i4);
        o.x += b0.x + b1.x; o.y += b0.y + b1.y;
        o.z += b0.z + b1.z; o.w += b0.w + b1.w;
    }
    *(float4*)(out + i4) = o;
}

// ---------------------------------------------------------------------------
extern "C" void kernel_launch(void* const* d_in, const int* in_sizes, int n_in,
                              void* d_out, int out_size, void* d_ws, size_t ws_size,
                              hipStream_t stream) {
    const float* x   = (const float*)d_in[0];   // [T, D]
    const float* rw  = (const float*)d_in[1];   // [E, D]
    const float* lnw = (const float*)d_in[2];   // [E, D]
    const float* wi  = (const float*)d_in[3];   // [E, F, D]
    const float* wo  = (const float*)d_in[4];   // [E, D, F]

    float* out    = (float*)d_out;                    // [T, D]
    float* logits = (float*)d_out + (size_t)T * D;    // [T, E]

    // Proven base layout (watermark 190,578,688 B). ffout0 OVERLAYS xn+wip
    // (dead after gemm1); ffout1 appended past the watermark (+50.33 MB,
    // confirmed present in r14: big path ran).
    char* ws = (char*)d_ws;
    unsigned short* xn     = (unsigned short*)(ws);               // 12.58 MB
    unsigned short* wip    = (unsigned short*)(ws + 12582912);    // 37.75 MB
    float*          ffout0 = (float*)(ws);                        // 50.33 MB overlay
    unsigned short* wop    = (unsigned short*)(ws + 50331648);    // 37.75 MB
    unsigned short* H      = (unsigned short*)(ws + 88080384);    // 16640 x 3072 bf16
    int*            offs   = (int*)(ws + 190316544);              // 64 B (9 ints)
    int*            sel    = (int*)(ws + 190316672);              // 32 KB
    float2*         w01    = (float2*)(ws + 190349440);           // 64 KB
    int*            lists  = (int*)(ws + 190414976);              // 64 KB
    float*          wlist  = (float*)(ws + 190480512);            // 64 KB
    float*          ffout1 = (float*)(ws + 190578688);            // 50.33 MB (optional)

    const bool big2 = ws_size >= 240910336ULL;   // deterministic per deployment
    const int nkh = big2 ? 2 : 1;
    const int kts = 48 / nkh;

    prep_kernel<<<36864 + T / 4, 256, 0, stream>>>(wi, wo, lnw, wip, wop,
                                                   x, rw, logits, xn,
                                                   sel, w01);

    lists_kernel<<<E, 256, 0, stream>>>(sel, w01, offs, lists, wlist);

    // worst-case grids (mt < 64 covers any expert imbalance); dead blocks exit
    gemm1_kernel<<<64 * 24 * 8, 256, 0, stream>>>(xn, wip, offs, lists, H);
    gemm2_kernel<<<nkh * 64 * 3 * 8, 512, 0, stream>>>(H, wop, offs, lists,
                                                       wlist, ffout0,
                                                       big2 ? ffout1 : ffout0,
                                                       kts);
    combine_kernel<<<T * D / 4 / 256, 256, 0, stream>>>(x, w01, ffout0,
                                                        big2 ? ffout1 : ffout0,
                                                        nkh, out);
}